// Round 1
// baseline (828.753 us; speedup 1.0000x reference)
//
#include <hip/hip_runtime.h>
#include <math.h>

// Problem constants (N = 1024)
#define NPAIRS   8192      // 1024 * 8
#define NROWS    81920     // NPAIRS * 10
#define NCOLS    4096
#define NCHUNK   8
#define CHUNK    (NCOLS / NCHUNK)   // 512
#define HT_LD    48        // 45 padded to 48 (float4-friendly), pad zeroed

// ws layout (total ~5.75 MB):
//   Ht    : float[4096 * 48]            @ 0
//   pbest : float[NROWS * NCHUNK]       @ 786432 B
//   pidx  : int  [NROWS * NCHUNK]       @ 786432 + 2621440 B

// ---------------------------------------------------------------------------
// Kernel 0: transpose H (45 x 4096) -> Ht (4096 x 48), zero the pad so the
// padded fma terms contribute exactly 0 (ws is poisoned 0xAA before launch).
__global__ void transpose_H_kernel(const float* __restrict__ H,
                                   float* __restrict__ Ht) {
    int k = blockIdx.x * blockDim.x + threadIdx.x;
    if (k >= NCOLS) return;
    #pragma unroll
    for (int d = 0; d < 45; ++d)
        Ht[k * HT_LD + d] = H[d * NCOLS + k];
    Ht[k * HT_LD + 45] = 0.f;
    Ht[k * HT_LD + 46] = 0.f;
    Ht[k * HT_LD + 47] = 0.f;
}

// ---------------------------------------------------------------------------
// Kernel 1: per-lane row dot products + running argmax over a column chunk.
// lane = row  (argmax entirely per-lane, no cross-lane reduce)
// wave = (row_group, chunk); column index wave-uniform -> scalar Ht loads.
__global__ __launch_bounds__(256) void scores_kernel(
        const float* __restrict__ x,   // (1024, 480)
        const float* __restrict__ S,   // (30, 2, 15)
        const float* __restrict__ T,   // (30, 15)
        const float* __restrict__ Ht,  // (4096, 48)
        float* __restrict__ pbest,     // (NROWS, NCHUNK)
        int*   __restrict__ pidx) {
    const int lane = threadIdx.x & 63;
    // wave id is wave-uniform by construction; readfirstlane makes it an SGPR
    // so all Ht addressing scalarizes (s_load broadcast to the wave).
    const int wid  = __builtin_amdgcn_readfirstlane(blockIdx.x * 4 + (threadIdx.x >> 6));
    const int chunk     = wid & (NCHUNK - 1);
    const int row_group = wid >> 3;          // [0, 1280)
    const int row  = row_group * 64 + lane;  // < 81920 exactly

    const int pair = row / 10;               // (a*8 + b)
    const int c2   = row - pair * 10;        // output "c" in [0,10)
    const int a    = pair >> 3;
    const int b    = pair & 7;

    // ---- Stage 1 inline: y[j] = sign(x0*S0 + x1*S1 - T - 1e-4), j in [0,45)
    // row uses x4[a, b, c, :] for c = 3*c2 .. 3*c2+2  (x4 = x.reshape(1024,8,30,2))
    const float* xp = x + a * 480 + b * 60;
    float y[48];
    #pragma unroll
    for (int j = 0; j < 45; ++j) {
        const int c = c2 * 3 + j / 15;       // constant-folded by unroll
        const int k = j % 15;
        const float x0 = xp[c * 2 + 0];
        const float x1 = xp[c * 2 + 1];
        float v = x0 * S[(c * 2 + 0) * 15 + k] + x1 * S[(c * 2 + 1) * 15 + k];
        v = v - T[c * 15 + k] - 1e-4f;
        y[j] = (v > 0.f) ? 1.f : ((v < 0.f) ? -1.f : 0.f);
    }
    y[45] = 0.f; y[46] = 0.f; y[47] = 0.f;

    // ---- Stage 2: dot(y, Ht[k]) for k in this chunk; track (best, idx).
    float best = -INFINITY;
    int   bidx = 0;
    const int k0 = chunk * CHUNK;
    for (int kk = 0; kk < CHUNK; kk += 2) {
        const int ka = k0 + kk;
        const float4* ha = (const float4*)(Ht + (size_t)ka * HT_LD);
        const float4* hb = (const float4*)(Ht + (size_t)(ka + 1) * HT_LD);
        // 2 columns x 2 accumulators each -> 4 independent fma chains
        float sa0 = 0.f, sa1 = 0.f, sb0 = 0.f, sb1 = 0.f;
        #pragma unroll
        for (int q = 0; q < 12; q += 2) {
            const float4 va0 = ha[q], va1 = ha[q + 1];
            const float4 vb0 = hb[q], vb1 = hb[q + 1];
            sa0 = fmaf(y[4*q + 0], va0.x, sa0);
            sa0 = fmaf(y[4*q + 1], va0.y, sa0);
            sa0 = fmaf(y[4*q + 2], va0.z, sa0);
            sa0 = fmaf(y[4*q + 3], va0.w, sa0);
            sa1 = fmaf(y[4*q + 4], va1.x, sa1);
            sa1 = fmaf(y[4*q + 5], va1.y, sa1);
            sa1 = fmaf(y[4*q + 6], va1.z, sa1);
            sa1 = fmaf(y[4*q + 7], va1.w, sa1);
            sb0 = fmaf(y[4*q + 0], vb0.x, sb0);
            sb0 = fmaf(y[4*q + 1], vb0.y, sb0);
            sb0 = fmaf(y[4*q + 2], vb0.z, sb0);
            sb0 = fmaf(y[4*q + 3], vb0.w, sb0);
            sb1 = fmaf(y[4*q + 4], vb1.x, sb1);
            sb1 = fmaf(y[4*q + 5], vb1.y, sb1);
            sb1 = fmaf(y[4*q + 6], vb1.z, sb1);
            sb1 = fmaf(y[4*q + 7], vb1.w, sb1);
        }
        const float sa = sa0 + sa1;
        const float sb = sb0 + sb1;
        // strict > keeps the FIRST index on ties (jnp.argmax semantics);
        // ka before ka+1 preserves ascending order.
        if (sa > best) { best = sa; bidx = ka; }
        if (sb > best) { best = sb; bidx = ka + 1; }
    }
    pbest[row * NCHUNK + chunk] = best;
    pidx [row * NCHUNK + chunk] = bidx;
}

// ---------------------------------------------------------------------------
// Kernel 2: fold the 8 chunk partials (ascending chunk order + strict > ==
// global first-index argmax), gather LUT, write out (1024,8,10,2).
__global__ void reduce_lut_kernel(const float* __restrict__ pbest,
                                  const int*   __restrict__ pidx,
                                  const float* __restrict__ LUT,  // (10,4096,2)
                                  float* __restrict__ out) {
    int row = blockIdx.x * blockDim.x + threadIdx.x;
    if (row >= NROWS) return;
    float best = -INFINITY;
    int   bidx = 0;
    #pragma unroll
    for (int ch = 0; ch < NCHUNK; ++ch) {
        const float bv = pbest[row * NCHUNK + ch];
        const int   bi = pidx [row * NCHUNK + ch];
        if (bv > best) { best = bv; bidx = bi; }
    }
    const int pair = row / 10;
    const int c2   = row - pair * 10;
    const float* l = LUT + ((size_t)c2 * NCOLS + bidx) * 2;
    out[row * 2 + 0] = l[0];
    out[row * 2 + 1] = l[1];
}

// ---------------------------------------------------------------------------
extern "C" void kernel_launch(void* const* d_in, const int* in_sizes, int n_in,
                              void* d_out, int out_size, void* d_ws, size_t ws_size,
                              hipStream_t stream) {
    const float* x   = (const float*)d_in[0];  // 1024*480
    const float* S   = (const float*)d_in[1];  // 30*2*15
    const float* T   = (const float*)d_in[2];  // 30*15
    const float* H   = (const float*)d_in[3];  // 45*4096
    const float* LUT = (const float*)d_in[4];  // 10*4096*2
    float* out = (float*)d_out;                // 1024*8*10*2

    float* Ht    = (float*)d_ws;                    // 4096*48 floats
    float* pbest = Ht + (size_t)NCOLS * HT_LD;      // NROWS*NCHUNK floats
    int*   pidx  = (int*)(pbest + (size_t)NROWS * NCHUNK);

    transpose_H_kernel<<<(NCOLS + 255) / 256, 256, 0, stream>>>(H, Ht);
    // 10240 waves = 1280 row-groups x 8 column chunks; 4 waves/block
    scores_kernel<<<10240 / 4, 256, 0, stream>>>(x, S, T, Ht, pbest, pidx);
    reduce_lut_kernel<<<(NROWS + 255) / 256, 256, 0, stream>>>(pbest, pidx, LUT, out);
}

// Round 2
// 243.203 us; speedup vs baseline: 3.4077x; 3.4077x over previous
//
#include <hip/hip_runtime.h>
#include <math.h>

// Problem constants (N = 1024)
#define M_ROWS  81920            // 1024*8*10 score rows
#define NCOLS   4096
#define KPAD    64               // 45 padded to 64 (2 MFMA k-tiles)
#define NCHUNK  4
#define CHUNKC  (NCOLS / NCHUNK) // 1024 cols per chunk
#define CTILES  (CHUNKC / 16)    // 64 col-tiles per chunk
#define LO_SCALE 4096.0f         // 2^12: keeps f16 residuals out of subnormal range
#define INV_LO   (1.0f / 4096.0f)

typedef _Float16 f16x8 __attribute__((ext_vector_type(8)));
typedef float    f32x4 __attribute__((ext_vector_type(4)));

// ws layout:
//   A    : _Float16[81920 * 64]   (y duplicated-free: hi and lo share A)  10.0 MB
//   Bhi  : _Float16[4096 * 64]    ([col][k], pad zeroed)                   0.5 MB
//   Blo  : _Float16[4096 * 64]    (residual * 2^12)                        0.5 MB
//   pbest: float[81920 * 4]                                                1.25 MB
//   pidx : int  [81920 * 4]                                                1.25 MB

// ---------------------------------------------------------------------------
// Build A: y[row][k] = sign(x4·S - T - 1e-4), exactly ±1/0 in f16. Pad k>=45.
__global__ void build_A_kernel(const float* __restrict__ x,
                               const float* __restrict__ S,
                               const float* __restrict__ T,
                               _Float16* __restrict__ A) {
    const int row = blockIdx.x * blockDim.x + threadIdx.x;
    if (row >= M_ROWS) return;
    const int pair = row / 10;
    const int c2   = row - pair * 10;
    const int a    = pair >> 3;
    const int b    = pair & 7;
    const float* xp = x + a * 480 + b * 60;
    _Float16 y[KPAD];
    #pragma unroll
    for (int j = 0; j < 45; ++j) {
        const int c = c2 * 3 + j / 15;    // constant-folded by unroll
        const int k = j % 15;
        const float x0 = xp[c * 2 + 0];
        const float x1 = xp[c * 2 + 1];
        float v = x0 * S[(c * 2 + 0) * 15 + k] + x1 * S[(c * 2 + 1) * 15 + k];
        v = v - T[c * 15 + k] - 1e-4f;
        y[j] = (v > 0.f) ? (_Float16)1.f : ((v < 0.f) ? (_Float16)-1.f : (_Float16)0.f);
    }
    #pragma unroll
    for (int j = 45; j < KPAD; ++j) y[j] = (_Float16)0.f;
    f16x8* dst = (f16x8*)(A + (size_t)row * KPAD);   // 128 B/row, 16B-aligned
    const f16x8* src = (const f16x8*)y;
    #pragma unroll
    for (int q = 0; q < KPAD / 8; ++q) dst[q] = src[q];
}

// ---------------------------------------------------------------------------
// Build B: split H (45 x 4096, [d][n]) into hi/lo f16 in [n][k] layout so the
// MFMA B-fragment (B[k=quad*8+j][n=lane&15]) is 8 contiguous halves per lane.
__global__ void build_B_kernel(const float* __restrict__ H,
                               _Float16* __restrict__ Bhi,
                               _Float16* __restrict__ Blo) {
    const int n = blockIdx.x * blockDim.x + threadIdx.x;
    if (n >= NCOLS) return;
    _Float16 hi[KPAD], lo[KPAD];
    #pragma unroll
    for (int k = 0; k < 45; ++k) {
        const float h = H[k * NCOLS + n];
        const _Float16 h1 = (_Float16)h;
        hi[k] = h1;
        lo[k] = (_Float16)((h - (float)h1) * LO_SCALE);
    }
    #pragma unroll
    for (int k = 45; k < KPAD; ++k) { hi[k] = (_Float16)0.f; lo[k] = (_Float16)0.f; }
    f16x8* dh = (f16x8*)(Bhi + (size_t)n * KPAD);
    f16x8* dl = (f16x8*)(Blo + (size_t)n * KPAD);
    const f16x8* sh = (const f16x8*)hi;
    const f16x8* sl = (const f16x8*)lo;
    #pragma unroll
    for (int q = 0; q < KPAD / 8; ++q) { dh[q] = sh[q]; dl[q] = sl[q]; }
}

// ---------------------------------------------------------------------------
// MFMA GEMM + fused argmax. wave = 64 rows (4 row-tiles) x 1024-col chunk.
// Block's 4 waves share the same chunk (L1 reuse on B), different row groups.
// C layout (m89-verified): row = quad*4 + reg, col = lane&15.
__global__ __launch_bounds__(256) void score_argmax_kernel(
        const _Float16* __restrict__ A,
        const _Float16* __restrict__ Bhi,
        const _Float16* __restrict__ Blo,
        float* __restrict__ pbest,
        int*   __restrict__ pidx) {
    const int tid  = threadIdx.x;
    const int lane = tid & 63;
    const int l15  = lane & 15;
    const int quad = lane >> 4;
    const int w    = blockIdx.x * 4 + (tid >> 6);     // [0, 5120)
    const int chunk = w / 1280;                        // block-uniform (1280 % 4 == 0)
    const int rg    = w - chunk * 1280;
    const int rowbase = rg * 64;

    // A fragments: A[m=lane&15][k=quad*8+j], 2 k-tiles x 4 row-tiles.
    f16x8 afr[4][2];
    #pragma unroll
    for (int rt = 0; rt < 4; ++rt)
        #pragma unroll
        for (int kt = 0; kt < 2; ++kt)
            afr[rt][kt] = *(const f16x8*)(A + (size_t)(rowbase + rt * 16 + l15) * KPAD
                                            + kt * 32 + quad * 8);

    float best[4][4];
    int   bidx[4][4];
    #pragma unroll
    for (int rt = 0; rt < 4; ++rt)
        #pragma unroll
        for (int r = 0; r < 4; ++r) { best[rt][r] = -INFINITY; bidx[rt][r] = 0; }

    const int colbase0 = chunk * CHUNKC;
    for (int ct = 0; ct < CTILES; ++ct) {
        const int colbase = colbase0 + ct * 16;
        const _Float16* bp = Bhi + (size_t)(colbase + l15) * KPAD + quad * 8;
        const _Float16* lp = Blo + (size_t)(colbase + l15) * KPAD + quad * 8;
        const f16x8 bh0 = *(const f16x8*)bp;
        const f16x8 bh1 = *(const f16x8*)(bp + 32);
        const f16x8 bl0 = *(const f16x8*)lp;
        const f16x8 bl1 = *(const f16x8*)(lp + 32);
        const int mycol = colbase + l15;
        #pragma unroll
        for (int rt = 0; rt < 4; ++rt) {
            f32x4 ch = {0.f, 0.f, 0.f, 0.f};
            f32x4 cl = {0.f, 0.f, 0.f, 0.f};
            ch = __builtin_amdgcn_mfma_f32_16x16x32_f16(afr[rt][0], bh0, ch, 0, 0, 0);
            ch = __builtin_amdgcn_mfma_f32_16x16x32_f16(afr[rt][1], bh1, ch, 0, 0, 0);
            cl = __builtin_amdgcn_mfma_f32_16x16x32_f16(afr[rt][0], bl0, cl, 0, 0, 0);
            cl = __builtin_amdgcn_mfma_f32_16x16x32_f16(afr[rt][1], bl1, cl, 0, 0, 0);
            #pragma unroll
            for (int r = 0; r < 4; ++r) {
                const float s = fmaf(cl[r], INV_LO, ch[r]);
                // per-lane cols ascend over ct -> strict > keeps first index
                if (s > best[rt][r]) { best[rt][r] = s; bidx[rt][r] = mycol; }
            }
        }
    }

    // Cross-lane argmax over the 16 cols held by l15=0..15 (same quad).
    // Tie -> smaller index (jnp.argmax first-index semantics).
    #pragma unroll
    for (int m = 1; m < 16; m <<= 1) {
        #pragma unroll
        for (int rt = 0; rt < 4; ++rt)
            #pragma unroll
            for (int r = 0; r < 4; ++r) {
                const float ov = __shfl_xor(best[rt][r], m, 64);
                const int   oi = __shfl_xor(bidx[rt][r], m, 64);
                if (ov > best[rt][r] ||
                    (ov == best[rt][r] && oi < bidx[rt][r])) {
                    best[rt][r] = ov; bidx[rt][r] = oi;
                }
            }
    }

    if (l15 == 0) {
        #pragma unroll
        for (int rt = 0; rt < 4; ++rt)
            #pragma unroll
            for (int r = 0; r < 4; ++r) {
                const int row = rowbase + rt * 16 + quad * 4 + r;
                pbest[(size_t)row * NCHUNK + chunk] = best[rt][r];
                pidx [(size_t)row * NCHUNK + chunk] = bidx[rt][r];
            }
    }
}

// ---------------------------------------------------------------------------
// Fold the 4 chunk partials (ascending chunk + strict > == global first-index
// argmax), gather LUT, write out (1024,8,10,2).
__global__ void reduce_lut_kernel(const float* __restrict__ pbest,
                                  const int*   __restrict__ pidx,
                                  const float* __restrict__ LUT,  // (10,4096,2)
                                  float* __restrict__ out) {
    const int row = blockIdx.x * blockDim.x + threadIdx.x;
    if (row >= M_ROWS) return;
    float best = -INFINITY;
    int   bi   = 0;
    #pragma unroll
    for (int ch = 0; ch < NCHUNK; ++ch) {
        const float bv = pbest[(size_t)row * NCHUNK + ch];
        const int   ix = pidx [(size_t)row * NCHUNK + ch];
        if (bv > best) { best = bv; bi = ix; }
    }
    const int pair = row / 10;
    const int c2   = row - pair * 10;
    const float* l = LUT + ((size_t)c2 * NCOLS + bi) * 2;
    out[row * 2 + 0] = l[0];
    out[row * 2 + 1] = l[1];
}

// ---------------------------------------------------------------------------
extern "C" void kernel_launch(void* const* d_in, const int* in_sizes, int n_in,
                              void* d_out, int out_size, void* d_ws, size_t ws_size,
                              hipStream_t stream) {
    const float* x   = (const float*)d_in[0];  // 1024*480
    const float* S   = (const float*)d_in[1];  // 30*2*15
    const float* T   = (const float*)d_in[2];  // 30*15
    const float* H   = (const float*)d_in[3];  // 45*4096
    const float* LUT = (const float*)d_in[4];  // 10*4096*2
    float* out = (float*)d_out;                // 1024*8*10*2

    _Float16* A   = (_Float16*)d_ws;                          // 81920*64
    _Float16* Bhi = A + (size_t)M_ROWS * KPAD;                // 4096*64
    _Float16* Blo = Bhi + (size_t)NCOLS * KPAD;               // 4096*64
    float*  pbest = (float*)(Blo + (size_t)NCOLS * KPAD);     // 81920*4
    int*    pidx  = (int*)(pbest + (size_t)M_ROWS * NCHUNK);  // 81920*4

    build_A_kernel<<<M_ROWS / 256, 256, 0, stream>>>(x, S, T, A);
    build_B_kernel<<<NCOLS / 256, 256, 0, stream>>>(H, Bhi, Blo);
    // 5120 waves = 1280 row-groups x 4 chunks; 4 waves/block, chunk-uniform blocks
    score_argmax_kernel<<<1280, 256, 0, stream>>>(A, Bhi, Blo, pbest, pidx);
    reduce_lut_kernel<<<M_ROWS / 256, 256, 0, stream>>>(pbest, pidx, LUT, out);
}